// Round 2
// baseline (5289.780 us; speedup 1.0000x reference)
//
#include <hip/hip_runtime.h>
#include <hip/hip_bf16.h>
#include <math.h>

// Problem constants
#define BB 4
#define CIN 64
#define DI 128       // D_INNER
#define NS 16        // D_STATE
#define HH 256
#define WW 256
#define HW 65536     // HH*WW (2^16)
#define NCH_P 33     // 1 + 2*NS

// ---------------------------------------------------------------- gaussian
__device__ __forceinline__ void gauss15(float* g) {
    float s = 0.f;
#pragma unroll
    for (int i = 0; i < 15; ++i) {
        float a = (float)i - 7.0f;
        g[i] = expf(-a * a / 18.0f);   // 2*sigma^2 = 18
        s += g[i];
    }
    float inv = 1.0f / s;
#pragma unroll
    for (int i = 0; i < 15; ++i) g[i] *= inv;
}

__device__ __forceinline__ float softplusf(float x) {
    return fmaxf(x, 0.f) + log1pf(expf(-fabsf(x)));
}

// ---------------------------------------------------------------- K1: in_proj (U half only), one batch
// Ub[o,p] = sum_c xb[c,p]*W[o,c] + bias[o], o in [0,DI)
__global__ __launch_bounds__(256) void k_inproj(
    const float* __restrict__ xb, const float* __restrict__ w,
    const float* __restrict__ bias, float* __restrict__ Ub) {
    int p = blockIdx.x * 256 + threadIdx.x;   // pixel in [0, HW)
    float xv[CIN];
#pragma unroll
    for (int c = 0; c < CIN; ++c) xv[c] = xb[(size_t)c * HW + p];
    for (int o = 0; o < DI; ++o) {
        float acc = bias[o];
        const float* wr = w + o * CIN;
#pragma unroll
        for (int c = 0; c < CIN; ++c) acc = fmaf(xv[c], wr[c], acc);
        Ub[(size_t)o * HW + p] = acc;
    }
}

// ---------------------------------------------------------------- K2: fused dw3x3+tanh+15x15 highpass, one batch
// grid: DI*16 blocks (channel, 16-row tile). LDS-resident separable blur.
#define TILE_H 16
__global__ __launch_bounds__(256) void k_conv(
    const float* __restrict__ Ub, const float* __restrict__ dww,
    const float* __restrict__ dwb, float* __restrict__ Ucb) {
    __shared__ float sU[32 * 256];        // input rows h0-8 .. h0+23; reused as H-blur output
    __shared__ float sC[30 * 272];        // Uc1 rows h0-7 .. h0+22, col-padded (+7 each side)
    int c  = blockIdx.x >> 4;
    int t  = blockIdx.x & 15;
    int h0 = t * TILE_H;
    int w  = threadIdx.x;

    const float* base = Ub + (size_t)c * HW;
#pragma unroll
    for (int i = 0; i < 32; ++i) {
        int hh = h0 + i - 8;
        sU[i * 256 + w] = (hh >= 0 && hh < HH) ? base[hh * WW + w] : 0.f;
    }
    __syncthreads();

    float wt[9];
#pragma unroll
    for (int i = 0; i < 9; ++i) wt[i] = dww[c * 9 + i];
    float bb = dwb[c];

    // Uc1 = tanh(0.5*(dw3x3(U)+bias)); rows outside image are ZERO (blur zero-pad)
#pragma unroll
    for (int i = 0; i < 30; ++i) {
        int r = h0 + i - 7;
        float v = 0.f;
        if (r >= 0 && r < HH) {
            float acc = bb;
#pragma unroll
            for (int ky = 0; ky < 3; ++ky) {
                const float* ur = sU + (i + ky) * 256;   // abs row r-1+ky
#pragma unroll
                for (int kx = 0; kx < 3; ++kx) {
                    int ww = w + kx - 1;
                    if (ww >= 0 && ww < WW) acc = fmaf(ur[ww], wt[ky * 3 + kx], acc);
                }
            }
            v = tanhf(0.5f * acc);
        }
        sC[i * 272 + w + 7] = v;
    }
    if (w < 7) {
#pragma unroll
        for (int i = 0; i < 30; ++i) { sC[i * 272 + w] = 0.f; sC[i * 272 + w + 263] = 0.f; }
    }
    __syncthreads();

    float g[15]; gauss15(g);
    // horizontal blur -> reuse sU (30x256). Each thread writes only column w.
#pragma unroll
    for (int i = 0; i < 30; ++i) {
        float acc = 0.f;
#pragma unroll
        for (int k = 0; k < 15; ++k) acc = fmaf(sC[i * 272 + w + k], g[k], acc);
        sU[i * 256 + w] = acc;
    }
    // vertical blur + subtract (reads own column only -> no barrier needed)
    float* outp = Ucb + (size_t)c * HW + h0 * WW + w;
#pragma unroll
    for (int i = 0; i < TILE_H; ++i) {
        float acc = 0.f;
#pragma unroll
        for (int k = 0; k < 15; ++k) acc = fmaf(sU[(i + k) * 256 + w], g[k], acc);
        float center = sC[(i + 7) * 272 + w + 7];
        outp[i * WW] = center - acc;
    }
}

// ---------------------------------------------------------------- K5: x_proj (128 -> 33), nb batches
__global__ __launch_bounds__(256) void k_xproj(
    const float* __restrict__ Uc, const float* __restrict__ xw,
    float* __restrict__ P) {
    int p = blockIdx.x * 256 + threadIdx.x;
    int b = p >> 16;
    int rem = p & 65535;
    const float* up = Uc + (size_t)b * DI * HW + rem;
    float acc[NCH_P];
#pragma unroll
    for (int o = 0; o < NCH_P; ++o) acc[o] = 0.f;
    for (int c = 0; c < DI; ++c) {
        float u = up[(size_t)c * HW];
#pragma unroll
        for (int o = 0; o < NCH_P; ++o) acc[o] = fmaf(u, xw[o * DI + c], acc[o]);
    }
    float* pp = P + (size_t)b * NCH_P * HW + rem;
#pragma unroll
    for (int o = 0; o < NCH_P; ++o) pp[(size_t)o * HW] = acc[o];
}

// ---------------------------------------------------------------- K6: scan along W (in-place), nb batches
// block = (b,h), threads = d (128). P channels: 0=delta, 1..16=B, 17..32=C
__global__ __launch_bounds__(128) void k_scan_w(
    float* __restrict__ UY, const float* __restrict__ P,
    const float* __restrict__ A_log, const float* __restrict__ dtw,
    const float* __restrict__ dtb, const float* __restrict__ Dv) {
    int bh = blockIdx.x;
    int b = bh >> 8;
    int h = bh & 255;
    int d = threadIdx.x;
    float Av[NS];
#pragma unroll
    for (int n = 0; n < NS; ++n) Av[n] = -expf(A_log[d * NS + n]);
    float wdt = dtw[d], bdt = dtb[d], Dd = Dv[d];
    float* urow = UY + ((size_t)(b * DI + d)) * HW + h * WW;
    const float* prow = P + ((size_t)b * NCH_P) * HW + h * WW;
    float hS[NS];
#pragma unroll
    for (int n = 0; n < NS; ++n) hS[n] = 0.f;
    for (int w = 0; w < WW; ++w) {
        float u = urow[w];
        float delta = prow[w];
        float dt = softplusf(fmaf(delta, wdt, bdt));
        float ud = u * dt;
        float y = Dd * u;
#pragma unroll
        for (int n = 0; n < NS; ++n) {
            float Bn = prow[(size_t)(1 + n) * HW + w];
            float Cn = prow[(size_t)(17 + n) * HW + w];
            float e = expf(dt * Av[n]);
            hS[n] = fmaf(e, hS[n], ud * Bn);
            y = fmaf(hS[n], Cn, y);
        }
        urow[w] = y;
    }
}

// ---------------------------------------------------------------- K7: scan along H (in-place), nb batches
// block = (b,d), threads = w (256). Fully coalesced.
__global__ __launch_bounds__(256) void k_scan_h(
    float* __restrict__ UY, const float* __restrict__ P,
    const float* __restrict__ A_log, const float* __restrict__ dtw,
    const float* __restrict__ dtb, const float* __restrict__ Dv) {
    int bd = blockIdx.x;
    int b = bd >> 7;
    int d = bd & (DI - 1);
    int w = threadIdx.x;
    float Av[NS];
#pragma unroll
    for (int n = 0; n < NS; ++n) Av[n] = -expf(A_log[d * NS + n]);
    float wdt = dtw[d], bdt = dtb[d], Dd = Dv[d];
    float* ucol = UY + (size_t)bd * HW + w;
    const float* pcol = P + ((size_t)b * NCH_P) * HW + w;
    float hS[NS];
#pragma unroll
    for (int n = 0; n < NS; ++n) hS[n] = 0.f;
    for (int h = 0; h < HH; ++h) {
        float u = ucol[h * WW];
        float delta = pcol[h * WW];
        float dt = softplusf(fmaf(delta, wdt, bdt));
        float ud = u * dt;
        float y = Dd * u;
#pragma unroll
        for (int n = 0; n < NS; ++n) {
            float Bn = pcol[(size_t)(1 + n) * HW + h * WW];
            float Cn = pcol[(size_t)(17 + n) * HW + h * WW];
            float e = expf(dt * Av[n]);
            hS[n] = fmaf(e, hS[n], ud * Bn);
            y = fmaf(hS[n], Cn, y);
        }
        ucol[h * WW] = y;
    }
}

// ---------------------------------------------------------------- K8: recompute Z, gate, out_proj (128 -> 64)
// Y is (nb,DI,HW); xb/outb are batch-offset views of x/out.
__global__ __launch_bounds__(256) void k_out(
    const float* __restrict__ Y, const float* __restrict__ xb,
    const float* __restrict__ wz, const float* __restrict__ bz,
    const float* __restrict__ ow, const float* __restrict__ ob,
    float* __restrict__ outb) {
    int p = blockIdx.x * 256 + threadIdx.x;
    int b = p >> 16;
    int rem = p & 65535;
    const float* yp = Y + (size_t)b * DI * HW + rem;
    const float* xp = xb + (size_t)b * CIN * HW + rem;
    float xv[CIN];
#pragma unroll
    for (int c = 0; c < CIN; ++c) xv[c] = xp[(size_t)c * HW];
    float acc[CIN];
#pragma unroll
    for (int c = 0; c < CIN; ++c) acc[c] = 0.f;
    for (int dd = 0; dd < DI; ++dd) {
        float yv = yp[(size_t)dd * HW];
        float z = bz[dd];
        const float* wr = wz + dd * CIN;
#pragma unroll
        for (int c = 0; c < CIN; ++c) z = fmaf(xv[c], wr[c], z);
        float gate = yv / (1.0f + expf(-z));
#pragma unroll
        for (int c = 0; c < CIN; ++c) acc[c] = fmaf(gate, ow[c * DI + dd], acc[c]);
    }
    float* op = outb + (size_t)b * CIN * HW + rem;
#pragma unroll
    for (int c = 0; c < CIN; ++c) op[(size_t)c * HW] = acc[c] + ob[c];
}

// ---------------------------------------------------------------- launch
extern "C" void kernel_launch(void* const* d_in, const int* in_sizes, int n_in,
                              void* d_out, int out_size, void* d_ws, size_t ws_size,
                              hipStream_t stream) {
    const float* x     = (const float*)d_in[0];
    const float* ipw   = (const float*)d_in[1];
    const float* ipb   = (const float*)d_in[2];
    const float* dww   = (const float*)d_in[3];
    const float* dwb   = (const float*)d_in[4];
    const float* xpw   = (const float*)d_in[5];
    const float* dtw   = (const float*)d_in[6];
    const float* dtb   = (const float*)d_in[7];
    const float* A_log = (const float*)d_in[8];
    const float* Dv    = (const float*)d_in[9];
    const float* ow    = (const float*)d_in[10];
    const float* ob    = (const float*)d_in[11];
    float* out = (float*)d_out;

    const float* wz = ipw + (size_t)DI * CIN;   // Z half of in_proj weight
    const float* bz = ipb + DI;                 // Z half of in_proj bias

    const size_t PLANE = (size_t)DI * HW;       // 8,388,608 floats per batch (U or Uc)
    const size_t NB    = (size_t)BB * PLANE;    // full 4-batch tensor

    if (ws_size >= (NB + PLANE) * sizeof(float)) {
        // ---------- Path A: full-batch scans. ws = Y(4 batches) + U(1 batch); P in d_out.
        float* bufY = (float*)d_ws;
        float* bufU = bufY + NB;
        float* P    = out;                       // 33*4*HW = 34.6 MB <= 67 MB; k_out overwrites last
        for (int b = 0; b < BB; ++b) {
            k_inproj<<<HW / 256, 256, 0, stream>>>(x + (size_t)b * CIN * HW, ipw, ipb, bufU);
            k_conv<<<DI * 16, 256, 0, stream>>>(bufU, dww, dwb, bufY + (size_t)b * PLANE);
        }
        k_xproj<<<BB * (HW / 256), 256, 0, stream>>>(bufY, xpw, P);
        k_scan_w<<<BB * HH, 128, 0, stream>>>(bufY, P, A_log, dtw, dtb, Dv);
        k_scan_h<<<BB * DI, 256, 0, stream>>>(bufY, P, A_log, dtw, dtb, Dv);
        k_out<<<BB * (HW / 256), 256, 0, stream>>>(bufY, x, wz, bz, ow, ob, out);
    } else {
        // ---------- Path B: fully batch-sequential. ws = U_b/P_b (overlapped) + Y_b = 64 MiB.
        float* bufA = (float*)d_ws;              // U_b, then P_b (U dead after k_conv)
        float* bufY = bufA + PLANE;              // Uc_b -> Y_h -> Y_v
        for (int b = 0; b < BB; ++b) {
            const float* xb = x + (size_t)b * CIN * HW;
            k_inproj<<<HW / 256, 256, 0, stream>>>(xb, ipw, ipb, bufA);
            k_conv<<<DI * 16, 256, 0, stream>>>(bufA, dww, dwb, bufY);
            k_xproj<<<HW / 256, 256, 0, stream>>>(bufY, xpw, bufA);
            k_scan_w<<<HH, 128, 0, stream>>>(bufY, bufA, A_log, dtw, dtb, Dv);
            k_scan_h<<<DI, 256, 0, stream>>>(bufY, bufA, A_log, dtw, dtb, Dv);
            k_out<<<HW / 256, 256, 0, stream>>>(bufY, xb, wz, bz, ow, ob, out + (size_t)b * CIN * HW);
        }
    }
}

// Round 3
// 2022.953 us; speedup vs baseline: 2.6149x; 2.6149x over previous
//
#include <hip/hip_runtime.h>
#include <hip/hip_bf16.h>
#include <math.h>

// Problem constants
#define BB 4
#define CIN 64
#define DI 128       // D_INNER
#define NS 16        // D_STATE
#define HH 256
#define WW 256
#define HW 65536     // HH*WW (2^16)
#define NCH_P 33     // 1 + 2*NS

// ---------------------------------------------------------------- fast math helpers
__device__ __forceinline__ float softplusf(float x) {
    // max(x,0) + log(1+exp(-|x|)); e in (0,1] so plain log is accurate enough
    return fmaxf(x, 0.f) + __logf(1.0f + __expf(-fabsf(x)));
}
__device__ __forceinline__ float tanh_half(float a) {   // tanh(0.5*a)
    return 1.0f - 2.0f / (1.0f + __expf(a));
}
__device__ __forceinline__ float sigmoidf(float z) {
    return 1.0f / (1.0f + __expf(-z));
}

__device__ __forceinline__ void gauss15(float* g) {
    float s = 0.f;
#pragma unroll
    for (int i = 0; i < 15; ++i) {
        float a = (float)i - 7.0f;
        g[i] = __expf(-a * a / 18.0f);   // 2*sigma^2 = 18
        s += g[i];
    }
    float inv = 1.0f / s;
#pragma unroll
    for (int i = 0; i < 15; ++i) g[i] *= inv;
}

// ---------------------------------------------------------------- K1: in_proj (U half only), one batch
__global__ __launch_bounds__(256) void k_inproj(
    const float* __restrict__ xb, const float* __restrict__ w,
    const float* __restrict__ bias, float* __restrict__ Ub) {
    int p = blockIdx.x * 256 + threadIdx.x;   // pixel in [0, HW)
    float xv[CIN];
#pragma unroll
    for (int c = 0; c < CIN; ++c) xv[c] = xb[(size_t)c * HW + p];
    for (int o = 0; o < DI; ++o) {
        float acc = bias[o];
        const float* wr = w + o * CIN;
#pragma unroll
        for (int c = 0; c < CIN; ++c) acc = fmaf(xv[c], wr[c], acc);
        Ub[(size_t)o * HW + p] = acc;
    }
}

// ---------------------------------------------------------------- K2: fused dw3x3+tanh+15x15 highpass, one batch
#define TILE_H 16
__global__ __launch_bounds__(256) void k_conv(
    const float* __restrict__ Ub, const float* __restrict__ dww,
    const float* __restrict__ dwb, float* __restrict__ Ucb) {
    __shared__ float sU[32 * 256];        // input rows h0-8 .. h0+23; reused as H-blur output
    __shared__ float sC[30 * 272];        // Uc1 rows h0-7 .. h0+22, col-padded (+7 each side)
    int c  = blockIdx.x >> 4;
    int t  = blockIdx.x & 15;
    int h0 = t * TILE_H;
    int w  = threadIdx.x;

    const float* base = Ub + (size_t)c * HW;
#pragma unroll
    for (int i = 0; i < 32; ++i) {
        int hh = h0 + i - 8;
        sU[i * 256 + w] = (hh >= 0 && hh < HH) ? base[hh * WW + w] : 0.f;
    }
    __syncthreads();

    float wt[9];
#pragma unroll
    for (int i = 0; i < 9; ++i) wt[i] = dww[c * 9 + i];
    float bb = dwb[c];

#pragma unroll
    for (int i = 0; i < 30; ++i) {
        int r = h0 + i - 7;
        float v = 0.f;
        if (r >= 0 && r < HH) {
            float acc = bb;
#pragma unroll
            for (int ky = 0; ky < 3; ++ky) {
                const float* ur = sU + (i + ky) * 256;
#pragma unroll
                for (int kx = 0; kx < 3; ++kx) {
                    int ww = w + kx - 1;
                    if (ww >= 0 && ww < WW) acc = fmaf(ur[ww], wt[ky * 3 + kx], acc);
                }
            }
            v = tanh_half(acc);
        }
        sC[i * 272 + w + 7] = v;
    }
    if (w < 7) {
#pragma unroll
        for (int i = 0; i < 30; ++i) { sC[i * 272 + w] = 0.f; sC[i * 272 + w + 263] = 0.f; }
    }
    __syncthreads();

    float g[15]; gauss15(g);
#pragma unroll
    for (int i = 0; i < 30; ++i) {
        float acc = 0.f;
#pragma unroll
        for (int k = 0; k < 15; ++k) acc = fmaf(sC[i * 272 + w + k], g[k], acc);
        sU[i * 256 + w] = acc;
    }
    float* outp = Ucb + (size_t)c * HW + h0 * WW + w;
#pragma unroll
    for (int i = 0; i < TILE_H; ++i) {
        float acc = 0.f;
#pragma unroll
        for (int k = 0; k < 15; ++k) acc = fmaf(sU[(i + k) * 256 + w], g[k], acc);
        float center = sC[(i + 7) * 272 + w + 7];
        outp[i * WW] = center - acc;
    }
}

// ---------------------------------------------------------------- K5: x_proj (128 -> 33), nb batches
__global__ __launch_bounds__(256) void k_xproj(
    const float* __restrict__ Uc, const float* __restrict__ xw,
    float* __restrict__ P) {
    int p = blockIdx.x * 256 + threadIdx.x;
    int b = p >> 16;
    int rem = p & 65535;
    const float* up = Uc + (size_t)b * DI * HW + rem;
    float acc[NCH_P];
#pragma unroll
    for (int o = 0; o < NCH_P; ++o) acc[o] = 0.f;
    for (int c = 0; c < DI; ++c) {
        float u = up[(size_t)c * HW];
#pragma unroll
        for (int o = 0; o < NCH_P; ++o) acc[o] = fmaf(u, xw[o * DI + c], acc[o]);
    }
    float* pp = P + (size_t)b * NCH_P * HW + rem;
#pragma unroll
    for (int o = 0; o < NCH_P; ++o) pp[(size_t)o * HW] = acc[o];
}

// ---------------------------------------------------------------- K6: scan along W, LDS-chunked
// block = (b,h), 128 threads (one per d). u staged via coalesced float4 through LDS;
// delta/B/C read wave-uniform from global -> scalar loads.
#define CW 32
__global__ __launch_bounds__(128) void k_scan_w(
    float* __restrict__ UY, const float* __restrict__ P,
    const float* __restrict__ A_log, const float* __restrict__ dtw,
    const float* __restrict__ dtb, const float* __restrict__ Dv) {
    __shared__ float sU[DI * 33];          // [d][w'] stride 33 -> 2-way bank = free
    int bh = blockIdx.x;
    int b = bh >> 8;
    int h = bh & 255;
    int t = threadIdx.x;                   // d

    float Av[NS];
#pragma unroll
    for (int n = 0; n < NS; ++n) Av[n] = -__expf(A_log[t * NS + n]);
    float wdt = dtw[t], bdt = dtb[t], Dd = Dv[t];
    float hS[NS];
#pragma unroll
    for (int n = 0; n < NS; ++n) hS[n] = 0.f;

    float* ubase = UY + (size_t)(b * DI) * HW + (size_t)h * WW;   // + d*HW + w
    const float* prow = P + (size_t)(b * NCH_P) * HW + (size_t)h * WW;

    const int w4 = (t & 7) * 4;            // float4 slot within a 32-wide chunk row
    const int dbase = t >> 3;              // rows d = dbase + 16*p

    for (int w0 = 0; w0 < WW; w0 += CW) {
        // ---- stage u chunk: 128 rows x 32 w, coalesced 128B segments
#pragma unroll
        for (int p = 0; p < 8; ++p) {
            int d = dbase + p * 16;
            const float4 v = *(const float4*)(ubase + (size_t)d * HW + w0 + w4);
            float* s = sU + d * 33 + w4;
            s[0] = v.x; s[1] = v.y; s[2] = v.z; s[3] = v.w;
        }
        __syncthreads();
        // ---- scan 32 steps out of LDS
#pragma unroll 4
        for (int wi = 0; wi < CW; ++wi) {
            float u = sU[t * 33 + wi];
            float delta = prow[w0 + wi];               // uniform -> s_load
            float dt = softplusf(fmaf(delta, wdt, bdt));
            float ud = u * dt;
            float y = Dd * u;
#pragma unroll
            for (int n = 0; n < NS; ++n) {
                float Bn = prow[(size_t)(1 + n) * HW + w0 + wi];    // uniform
                float Cn = prow[(size_t)(17 + n) * HW + w0 + wi];   // uniform
                float e = __expf(dt * Av[n]);
                hS[n] = fmaf(e, hS[n], ud * Bn);
                y = fmaf(hS[n], Cn, y);
            }
            sU[t * 33 + wi] = y;                        // in-place (own slot)
        }
        __syncthreads();
        // ---- write back y chunk, coalesced float4
#pragma unroll
        for (int p = 0; p < 8; ++p) {
            int d = dbase + p * 16;
            const float* s = sU + d * 33 + w4;
            float4 v; v.x = s[0]; v.y = s[1]; v.z = s[2]; v.w = s[3];
            *(float4*)(ubase + (size_t)d * HW + w0 + w4) = v;
        }
        __syncthreads();
    }
}

// ---------------------------------------------------------------- K7: scan along H, software-pipelined
// block = (b,d), threads = w (256). Fully coalesced; prefetch next row while computing.
__global__ __launch_bounds__(256) void k_scan_h(
    float* __restrict__ UY, const float* __restrict__ P,
    const float* __restrict__ A_log, const float* __restrict__ dtw,
    const float* __restrict__ dtb, const float* __restrict__ Dv) {
    int bd = blockIdx.x;
    int b = bd >> 7;
    int d = bd & (DI - 1);
    int w = threadIdx.x;
    float Av[NS];
#pragma unroll
    for (int n = 0; n < NS; ++n) Av[n] = -__expf(A_log[d * NS + n]);   // uniform
    float wdt = dtw[d], bdt = dtb[d], Dd = Dv[d];
    float* ucol = UY + (size_t)bd * HW + w;
    const float* pcol = P + (size_t)(b * NCH_P) * HW + w;
    float hS[NS];
#pragma unroll
    for (int n = 0; n < NS; ++n) hS[n] = 0.f;

    // prefetch row 0
    float u_c = ucol[0];
    float de_c = pcol[0];
    float Bc[NS], Cc[NS];
#pragma unroll
    for (int n = 0; n < NS; ++n) {
        Bc[n] = pcol[(size_t)(1 + n) * HW];
        Cc[n] = pcol[(size_t)(17 + n) * HW];
    }
    for (int h = 0; h < HH; ++h) {
        float u_nx = 0.f, de_nx = 0.f, Bn_nx[NS], Cn_nx[NS];
        if (h + 1 < HH) {
            size_t off = (size_t)(h + 1) * WW;
            u_nx = ucol[off];
            de_nx = pcol[off];
#pragma unroll
            for (int n = 0; n < NS; ++n) {
                Bn_nx[n] = pcol[(size_t)(1 + n) * HW + off];
                Cn_nx[n] = pcol[(size_t)(17 + n) * HW + off];
            }
        }
        float dt = softplusf(fmaf(de_c, wdt, bdt));
        float ud = u_c * dt;
        float y = Dd * u_c;
#pragma unroll
        for (int n = 0; n < NS; ++n) {
            float e = __expf(dt * Av[n]);
            hS[n] = fmaf(e, hS[n], ud * Bc[n]);
            y = fmaf(hS[n], Cc[n], y);
        }
        ucol[(size_t)h * WW] = y;
        u_c = u_nx; de_c = de_nx;
#pragma unroll
        for (int n = 0; n < NS; ++n) { Bc[n] = Bn_nx[n]; Cc[n] = Cn_nx[n]; }
    }
}

// ---------------------------------------------------------------- K8: recompute Z, gate, out_proj (128 -> 64)
__global__ __launch_bounds__(256) void k_out(
    const float* __restrict__ Y, const float* __restrict__ xb,
    const float* __restrict__ wz, const float* __restrict__ bz,
    const float* __restrict__ ow, const float* __restrict__ ob,
    float* __restrict__ outb) {
    int p = blockIdx.x * 256 + threadIdx.x;
    int b = p >> 16;
    int rem = p & 65535;
    const float* yp = Y + (size_t)b * DI * HW + rem;
    const float* xp = xb + (size_t)b * CIN * HW + rem;
    float xv[CIN];
#pragma unroll
    for (int c = 0; c < CIN; ++c) xv[c] = xp[(size_t)c * HW];
    float acc[CIN];
#pragma unroll
    for (int c = 0; c < CIN; ++c) acc[c] = 0.f;
    for (int dd = 0; dd < DI; ++dd) {
        float yv = yp[(size_t)dd * HW];
        float z = bz[dd];
        const float* wr = wz + dd * CIN;
#pragma unroll
        for (int c = 0; c < CIN; ++c) z = fmaf(xv[c], wr[c], z);
        float gate = yv * sigmoidf(z);
#pragma unroll
        for (int c = 0; c < CIN; ++c) acc[c] = fmaf(gate, ow[c * DI + dd], acc[c]);
    }
    float* op = outb + (size_t)b * CIN * HW + rem;
#pragma unroll
    for (int c = 0; c < CIN; ++c) op[(size_t)c * HW] = acc[c] + ob[c];
}

// ---------------------------------------------------------------- launch
extern "C" void kernel_launch(void* const* d_in, const int* in_sizes, int n_in,
                              void* d_out, int out_size, void* d_ws, size_t ws_size,
                              hipStream_t stream) {
    const float* x     = (const float*)d_in[0];
    const float* ipw   = (const float*)d_in[1];
    const float* ipb   = (const float*)d_in[2];
    const float* dww   = (const float*)d_in[3];
    const float* dwb   = (const float*)d_in[4];
    const float* xpw   = (const float*)d_in[5];
    const float* dtw   = (const float*)d_in[6];
    const float* dtb   = (const float*)d_in[7];
    const float* A_log = (const float*)d_in[8];
    const float* Dv    = (const float*)d_in[9];
    const float* ow    = (const float*)d_in[10];
    const float* ob    = (const float*)d_in[11];
    float* out = (float*)d_out;

    const float* wz = ipw + (size_t)DI * CIN;   // Z half of in_proj weight
    const float* bz = ipb + DI;                 // Z half of in_proj bias

    const size_t PLANE = (size_t)DI * HW;       // per-batch plane (floats)
    const size_t NB    = (size_t)BB * PLANE;

    if (ws_size >= (NB + PLANE) * sizeof(float)) {
        // ---------- Path A: full-batch scans. ws = Y(4) + U(1); P staged in d_out.
        float* bufY = (float*)d_ws;
        float* bufU = bufY + NB;
        float* P    = out;                       // 34.6 MB <= 67 MB; k_out overwrites last
        for (int b = 0; b < BB; ++b) {
            k_inproj<<<HW / 256, 256, 0, stream>>>(x + (size_t)b * CIN * HW, ipw, ipb, bufU);
            k_conv<<<DI * 16, 256, 0, stream>>>(bufU, dww, dwb, bufY + (size_t)b * PLANE);
        }
        k_xproj<<<BB * (HW / 256), 256, 0, stream>>>(bufY, xpw, P);
        k_scan_w<<<BB * HH, 128, 0, stream>>>(bufY, P, A_log, dtw, dtb, Dv);
        k_scan_h<<<BB * DI, 256, 0, stream>>>(bufY, P, A_log, dtw, dtb, Dv);
        k_out<<<BB * (HW / 256), 256, 0, stream>>>(bufY, x, wz, bz, ow, ob, out);
    } else {
        // ---------- Path B: batch-sequential. ws = U_b/P_b (overlapped) + Y_b.
        float* bufA = (float*)d_ws;
        float* bufY = bufA + PLANE;
        for (int b = 0; b < BB; ++b) {
            const float* xb = x + (size_t)b * CIN * HW;
            k_inproj<<<HW / 256, 256, 0, stream>>>(xb, ipw, ipb, bufA);
            k_conv<<<DI * 16, 256, 0, stream>>>(bufA, dww, dwb, bufY);
            k_xproj<<<HW / 256, 256, 0, stream>>>(bufY, xpw, bufA);
            k_scan_w<<<HH, 128, 0, stream>>>(bufY, bufA, A_log, dtw, dtb, Dv);
            k_scan_h<<<DI, 256, 0, stream>>>(bufY, bufA, A_log, dtw, dtb, Dv);
            k_out<<<HW / 256, 256, 0, stream>>>(bufY, xb, wz, bz, ow, ob, out + (size_t)b * CIN * HW);
        }
    }
}

// Round 4
// 1800.971 us; speedup vs baseline: 2.9372x; 1.1233x over previous
//
#include <hip/hip_runtime.h>
#include <hip/hip_bf16.h>
#include <math.h>

// Problem constants
#define BB 4
#define CIN 64
#define DI 128       // D_INNER
#define NS 16        // D_STATE
#define HH 256
#define WW 256
#define HW 65536     // HH*WW (2^16)
#define NCH_P 33     // 1 + 2*NS

// ---------------------------------------------------------------- fast math helpers
__device__ __forceinline__ float softplusf(float x) {
    return fmaxf(x, 0.f) + __logf(1.0f + __expf(-fabsf(x)));
}
__device__ __forceinline__ float tanh_half(float a) {   // tanh(0.5*a)
    return 1.0f - 2.0f / (1.0f + __expf(a));
}
__device__ __forceinline__ float sigmoidf(float z) {
    return 1.0f / (1.0f + __expf(-z));
}

__device__ __forceinline__ void gauss15(float* g) {
    float s = 0.f;
#pragma unroll
    for (int i = 0; i < 15; ++i) {
        float a = (float)i - 7.0f;
        g[i] = __expf(-a * a / 18.0f);   // 2*sigma^2 = 18
        s += g[i];
    }
    float inv = 1.0f / s;
#pragma unroll
    for (int i = 0; i < 15; ++i) g[i] *= inv;
}

// ---------------------------------------------------------------- K1: in_proj (U half only), one batch
__global__ __launch_bounds__(256) void k_inproj(
    const float* __restrict__ xb, const float* __restrict__ w,
    const float* __restrict__ bias, float* __restrict__ Ub) {
    int p = blockIdx.x * 256 + threadIdx.x;
    float xv[CIN];
#pragma unroll
    for (int c = 0; c < CIN; ++c) xv[c] = xb[(size_t)c * HW + p];
    for (int o = 0; o < DI; ++o) {
        float acc = bias[o];
        const float* wr = w + o * CIN;
#pragma unroll
        for (int c = 0; c < CIN; ++c) acc = fmaf(xv[c], wr[c], acc);
        Ub[(size_t)o * HW + p] = acc;
    }
}

// ---------------------------------------------------------------- K2: fused dw3x3+tanh+15x15 highpass, one batch
#define TILE_H 16
__global__ __launch_bounds__(256) void k_conv(
    const float* __restrict__ Ub, const float* __restrict__ dww,
    const float* __restrict__ dwb, float* __restrict__ Ucb) {
    __shared__ float sU[32 * 256];
    __shared__ float sC[30 * 272];
    int c  = blockIdx.x >> 4;
    int t  = blockIdx.x & 15;
    int h0 = t * TILE_H;
    int w  = threadIdx.x;

    const float* base = Ub + (size_t)c * HW;
#pragma unroll
    for (int i = 0; i < 32; ++i) {
        int hh = h0 + i - 8;
        sU[i * 256 + w] = (hh >= 0 && hh < HH) ? base[hh * WW + w] : 0.f;
    }
    __syncthreads();

    float wt[9];
#pragma unroll
    for (int i = 0; i < 9; ++i) wt[i] = dww[c * 9 + i];
    float bb = dwb[c];

#pragma unroll
    for (int i = 0; i < 30; ++i) {
        int r = h0 + i - 7;
        float v = 0.f;
        if (r >= 0 && r < HH) {
            float acc = bb;
#pragma unroll
            for (int ky = 0; ky < 3; ++ky) {
                const float* ur = sU + (i + ky) * 256;
#pragma unroll
                for (int kx = 0; kx < 3; ++kx) {
                    int ww = w + kx - 1;
                    if (ww >= 0 && ww < WW) acc = fmaf(ur[ww], wt[ky * 3 + kx], acc);
                }
            }
            v = tanh_half(acc);
        }
        sC[i * 272 + w + 7] = v;
    }
    if (w < 7) {
#pragma unroll
        for (int i = 0; i < 30; ++i) { sC[i * 272 + w] = 0.f; sC[i * 272 + w + 263] = 0.f; }
    }
    __syncthreads();

    float g[15]; gauss15(g);
#pragma unroll
    for (int i = 0; i < 30; ++i) {
        float acc = 0.f;
#pragma unroll
        for (int k = 0; k < 15; ++k) acc = fmaf(sC[i * 272 + w + k], g[k], acc);
        sU[i * 256 + w] = acc;
    }
    float* outp = Ucb + (size_t)c * HW + h0 * WW + w;
#pragma unroll
    for (int i = 0; i < TILE_H; ++i) {
        float acc = 0.f;
#pragma unroll
        for (int k = 0; k < 15; ++k) acc = fmaf(sU[(i + k) * 256 + w], g[k], acc);
        float center = sC[(i + 7) * 272 + w + 7];
        outp[i * WW] = center - acc;
    }
}

// ---------------------------------------------------------------- K5: x_proj (128 -> 33), nb batches
__global__ __launch_bounds__(256) void k_xproj(
    const float* __restrict__ Uc, const float* __restrict__ xw,
    float* __restrict__ P) {
    int p = blockIdx.x * 256 + threadIdx.x;
    int b = p >> 16;
    int rem = p & 65535;
    const float* up = Uc + (size_t)b * DI * HW + rem;
    float acc[NCH_P];
#pragma unroll
    for (int o = 0; o < NCH_P; ++o) acc[o] = 0.f;
    for (int c = 0; c < DI; ++c) {
        float u = up[(size_t)c * HW];
#pragma unroll
        for (int o = 0; o < NCH_P; ++o) acc[o] = fmaf(u, xw[o * DI + c], acc[o]);
    }
    float* pp = P + (size_t)b * NCH_P * HW + rem;
#pragma unroll
    for (int o = 0; o < NCH_P; ++o) pp[(size_t)o * HW] = acc[o];
}

// ---------------------------------------------------------------- K6: scan along W, LDS-staged u AND P, reg-prefetch
// block = (b,h), 128 threads (one per d).
#define CW 32
__global__ __launch_bounds__(128) void k_scan_w(
    float* __restrict__ UY, const float* __restrict__ P,
    const float* __restrict__ A_log, const float* __restrict__ dtw,
    const float* __restrict__ dtb, const float* __restrict__ Dv) {
    __shared__ float sU[DI * 33];          // [d][w'] stride 33 -> conflict-free
    __shared__ float sP[CW * 36];          // [w'][ch] stride 36 (144B, 16B-aligned rows)
    int bh = blockIdx.x;
    int b = bh >> 8;
    int h = bh & 255;
    int t = threadIdx.x;                   // d

    float Av[NS];
#pragma unroll
    for (int n = 0; n < NS; ++n) Av[n] = -__expf(A_log[t * NS + n]);
    float wdt = dtw[t], bdt = dtb[t], Dd = Dv[t];
    float hS[NS];
#pragma unroll
    for (int n = 0; n < NS; ++n) hS[n] = 0.f;

    float* ubase = UY + (size_t)(b * DI) * HW + (size_t)h * WW;
    const float* prow = P + (size_t)(b * NCH_P) * HW + (size_t)h * WW;

    const int w4 = (t & 7) * 4;
    const int dbase = t >> 3;

    float4 rU[8];
    float rP[9];
    // ---- prefetch chunk 0
#pragma unroll
    for (int p = 0; p < 8; ++p)
        rU[p] = *(const float4*)(ubase + (size_t)(dbase + p * 16) * HW + w4);
#pragma unroll
    for (int i = 0; i < 9; ++i) {
        int idx = i * 128 + t, ch = idx >> 5, wi = idx & 31;
        rP[i] = (ch < NCH_P) ? prow[(size_t)ch * HW + wi] : 0.f;
    }

    for (int w0 = 0; w0 < WW; w0 += CW) {
        // ---- commit staged regs to LDS
#pragma unroll
        for (int p = 0; p < 8; ++p) {
            float* s = sU + (dbase + p * 16) * 33 + w4;
            s[0] = rU[p].x; s[1] = rU[p].y; s[2] = rU[p].z; s[3] = rU[p].w;
        }
#pragma unroll
        for (int i = 0; i < 9; ++i) {
            int idx = i * 128 + t, ch = idx >> 5, wi = idx & 31;
            if (ch < NCH_P) sP[wi * 36 + ch] = rP[i];
        }
        __syncthreads();
        // ---- issue prefetch of next chunk (in flight during compute)
        if (w0 + CW < WW) {
#pragma unroll
            for (int p = 0; p < 8; ++p)
                rU[p] = *(const float4*)(ubase + (size_t)(dbase + p * 16) * HW + w0 + CW + w4);
#pragma unroll
            for (int i = 0; i < 9; ++i) {
                int idx = i * 128 + t, ch = idx >> 5, wi = idx & 31;
                rP[i] = (ch < NCH_P) ? prow[(size_t)ch * HW + w0 + CW + wi] : 0.f;
            }
        }
        // ---- scan 32 steps entirely out of LDS
#pragma unroll 2
        for (int wi = 0; wi < CW; ++wi) {
            const float* pr = sP + wi * 36;
            float4 q0 = *(const float4*)(pr);
            float4 q1 = *(const float4*)(pr + 4);
            float4 q2 = *(const float4*)(pr + 8);
            float4 q3 = *(const float4*)(pr + 12);
            float4 q4 = *(const float4*)(pr + 16);
            float4 q5 = *(const float4*)(pr + 20);
            float4 q6 = *(const float4*)(pr + 24);
            float4 q7 = *(const float4*)(pr + 28);
            float q8 = pr[32];
            float u = sU[t * 33 + wi];
            float dt = softplusf(fmaf(q0.x, wdt, bdt));
            float ud = u * dt;
            float y = Dd * u;
            float Bv[NS] = {q0.y,q0.z,q0.w,q1.x,q1.y,q1.z,q1.w,q2.x,
                            q2.y,q2.z,q2.w,q3.x,q3.y,q3.z,q3.w,q4.x};
            float Cv[NS] = {q4.y,q4.z,q4.w,q5.x,q5.y,q5.z,q5.w,q6.x,
                            q6.y,q6.z,q6.w,q7.x,q7.y,q7.z,q7.w,q8};
#pragma unroll
            for (int n = 0; n < NS; ++n) {
                float e = __expf(dt * Av[n]);
                hS[n] = fmaf(e, hS[n], ud * Bv[n]);
                y = fmaf(hS[n], Cv[n], y);
            }
            sU[t * 33 + wi] = y;
        }
        __syncthreads();
        // ---- write back y chunk, coalesced float4
#pragma unroll
        for (int p = 0; p < 8; ++p) {
            const float* s = sU + (dbase + p * 16) * 33 + w4;
            float4 v; v.x = s[0]; v.y = s[1]; v.z = s[2]; v.w = s[3];
            *(float4*)(ubase + (size_t)(dbase + p * 16) * HW + w0 + w4) = v;
        }
        __syncthreads();   // protect sU/sP against next iteration's staging
    }
}

// ---------------------------------------------------------------- K7: scan along H, unroll x2, prefetch depth 2
// block = (b,d), threads = w (256). Fully coalesced.
__global__ __launch_bounds__(256) void k_scan_h(
    float* __restrict__ UY, const float* __restrict__ P,
    const float* __restrict__ A_log, const float* __restrict__ dtw,
    const float* __restrict__ dtb, const float* __restrict__ Dv) {
    int bd = blockIdx.x;
    int b = bd >> 7;
    int d = bd & (DI - 1);
    int w = threadIdx.x;
    float Av[NS];
#pragma unroll
    for (int n = 0; n < NS; ++n) Av[n] = -__expf(A_log[d * NS + n]);
    float wdt = dtw[d], bdt = dtb[d], Dd = Dv[d];
    float* ucol = UY + (size_t)bd * HW + w;
    const float* pcol = P + (size_t)(b * NCH_P) * HW + w;
    float hS[NS];
#pragma unroll
    for (int n = 0; n < NS; ++n) hS[n] = 0.f;

    float uA, deA, BA[NS], CA[NS];
    float uB, deB, Bb[NS], Cb[NS];
    // prologue: rows 0,1
    uA = ucol[0]; deA = pcol[0];
#pragma unroll
    for (int n = 0; n < NS; ++n) { BA[n] = pcol[(size_t)(1 + n) * HW]; CA[n] = pcol[(size_t)(17 + n) * HW]; }
    uB = ucol[WW]; deB = pcol[WW];
#pragma unroll
    for (int n = 0; n < NS; ++n) { Bb[n] = pcol[(size_t)(1 + n) * HW + WW]; Cb[n] = pcol[(size_t)(17 + n) * HW + WW]; }

    for (int h = 0; h < HH; h += 2) {
        // issue prefetch of rows h+2, h+3 (clamped; values unused on tail)
        size_t o2 = (size_t)min(h + 2, HH - 1) * WW;
        size_t o3 = (size_t)min(h + 3, HH - 1) * WW;
        float u2 = ucol[o2], de2 = pcol[o2];
        float u3 = ucol[o3], de3 = pcol[o3];
        float B2[NS], C2[NS], B3[NS], C3[NS];
#pragma unroll
        for (int n = 0; n < NS; ++n) {
            B2[n] = pcol[(size_t)(1 + n) * HW + o2];
            C2[n] = pcol[(size_t)(17 + n) * HW + o2];
            B3[n] = pcol[(size_t)(1 + n) * HW + o3];
            C3[n] = pcol[(size_t)(17 + n) * HW + o3];
        }
        // step h (regs A)
        {
            float dt = softplusf(fmaf(deA, wdt, bdt));
            float ud = uA * dt;
            float y = Dd * uA;
#pragma unroll
            for (int n = 0; n < NS; ++n) {
                float e = __expf(dt * Av[n]);
                hS[n] = fmaf(e, hS[n], ud * BA[n]);
                y = fmaf(hS[n], CA[n], y);
            }
            ucol[(size_t)h * WW] = y;
        }
        // step h+1 (regs B)
        {
            float dt = softplusf(fmaf(deB, wdt, bdt));
            float ud = uB * dt;
            float y = Dd * uB;
#pragma unroll
            for (int n = 0; n < NS; ++n) {
                float e = __expf(dt * Av[n]);
                hS[n] = fmaf(e, hS[n], ud * Bb[n]);
                y = fmaf(hS[n], Cb[n], y);
            }
            ucol[(size_t)(h + 1) * WW] = y;
        }
        uA = u2; deA = de2; uB = u3; deB = de3;
#pragma unroll
        for (int n = 0; n < NS; ++n) { BA[n] = B2[n]; CA[n] = C2[n]; Bb[n] = B3[n]; Cb[n] = C3[n]; }
    }
}

// ---------------------------------------------------------------- K8: recompute Z, gate, out_proj (128 -> 64)
__global__ __launch_bounds__(256) void k_out(
    const float* __restrict__ Y, const float* __restrict__ xb,
    const float* __restrict__ wz, const float* __restrict__ bz,
    const float* __restrict__ ow, const float* __restrict__ ob,
    float* __restrict__ outb) {
    int p = blockIdx.x * 256 + threadIdx.x;
    int b = p >> 16;
    int rem = p & 65535;
    const float* yp = Y + (size_t)b * DI * HW + rem;
    const float* xp = xb + (size_t)b * CIN * HW + rem;
    float xv[CIN];
#pragma unroll
    for (int c = 0; c < CIN; ++c) xv[c] = xp[(size_t)c * HW];
    float acc[CIN];
#pragma unroll
    for (int c = 0; c < CIN; ++c) acc[c] = 0.f;
    for (int dd = 0; dd < DI; ++dd) {
        float yv = yp[(size_t)dd * HW];
        float z = bz[dd];
        const float* wr = wz + dd * CIN;
#pragma unroll
        for (int c = 0; c < CIN; ++c) z = fmaf(xv[c], wr[c], z);
        float gate = yv * sigmoidf(z);
#pragma unroll
        for (int c = 0; c < CIN; ++c) acc[c] = fmaf(gate, ow[c * DI + dd], acc[c]);
    }
    float* op = outb + (size_t)b * CIN * HW + rem;
#pragma unroll
    for (int c = 0; c < CIN; ++c) op[(size_t)c * HW] = acc[c] + ob[c];
}

// ---------------------------------------------------------------- launch
extern "C" void kernel_launch(void* const* d_in, const int* in_sizes, int n_in,
                              void* d_out, int out_size, void* d_ws, size_t ws_size,
                              hipStream_t stream) {
    const float* x     = (const float*)d_in[0];
    const float* ipw   = (const float*)d_in[1];
    const float* ipb   = (const float*)d_in[2];
    const float* dww   = (const float*)d_in[3];
    const float* dwb   = (const float*)d_in[4];
    const float* xpw   = (const float*)d_in[5];
    const float* dtw   = (const float*)d_in[6];
    const float* dtb   = (const float*)d_in[7];
    const float* A_log = (const float*)d_in[8];
    const float* Dv    = (const float*)d_in[9];
    const float* ow    = (const float*)d_in[10];
    const float* ob    = (const float*)d_in[11];
    float* out = (float*)d_out;

    const float* wz = ipw + (size_t)DI * CIN;
    const float* bz = ipb + DI;

    const size_t PLANE = (size_t)DI * HW;
    const size_t NB    = (size_t)BB * PLANE;

    if (ws_size >= (NB + PLANE) * sizeof(float)) {
        // ---------- Path A: full-batch scans. ws = Y(4) + U(1); P staged in d_out.
        float* bufY = (float*)d_ws;
        float* bufU = bufY + NB;
        float* P    = out;
        for (int b = 0; b < BB; ++b) {
            k_inproj<<<HW / 256, 256, 0, stream>>>(x + (size_t)b * CIN * HW, ipw, ipb, bufU);
            k_conv<<<DI * 16, 256, 0, stream>>>(bufU, dww, dwb, bufY + (size_t)b * PLANE);
        }
        k_xproj<<<BB * (HW / 256), 256, 0, stream>>>(bufY, xpw, P);
        k_scan_w<<<BB * HH, 128, 0, stream>>>(bufY, P, A_log, dtw, dtb, Dv);
        k_scan_h<<<BB * DI, 256, 0, stream>>>(bufY, P, A_log, dtw, dtb, Dv);
        k_out<<<BB * (HW / 256), 256, 0, stream>>>(bufY, x, wz, bz, ow, ob, out);
    } else {
        // ---------- Path B: batch-sequential. ws = U_b/P_b (overlapped) + Y_b.
        float* bufA = (float*)d_ws;
        float* bufY = bufA + PLANE;
        for (int b = 0; b < BB; ++b) {
            const float* xb = x + (size_t)b * CIN * HW;
            k_inproj<<<HW / 256, 256, 0, stream>>>(xb, ipw, ipb, bufA);
            k_conv<<<DI * 16, 256, 0, stream>>>(bufA, dww, dwb, bufY);
            k_xproj<<<HW / 256, 256, 0, stream>>>(bufY, xpw, bufA);
            k_scan_w<<<HH, 128, 0, stream>>>(bufY, bufA, A_log, dtw, dtb, Dv);
            k_scan_h<<<DI, 256, 0, stream>>>(bufY, bufA, A_log, dtw, dtb, Dv);
            k_out<<<HW / 256, 256, 0, stream>>>(bufY, xb, wz, bz, ow, ob, out + (size_t)b * CIN * HW);
        }
    }
}

// Round 5
// 1551.399 us; speedup vs baseline: 3.4097x; 1.1609x over previous
//
#include <hip/hip_runtime.h>
#include <hip/hip_bf16.h>
#include <math.h>

// Problem constants
#define BB 4
#define CIN 64
#define DI 128       // D_INNER
#define NS 16        // D_STATE
#define HH 256
#define WW 256
#define HW 65536     // HH*WW (2^16)
#define NCH_P 33     // 1 + 2*NS

// ---------------------------------------------------------------- fast math helpers
__device__ __forceinline__ float softplusf(float x) {
    return fmaxf(x, 0.f) + __logf(1.0f + __expf(-fabsf(x)));
}
__device__ __forceinline__ float tanh_half(float a) {   // tanh(0.5*a)
    return 1.0f - 2.0f / (1.0f + __expf(a));
}
__device__ __forceinline__ float sigmoidf(float z) {
    return 1.0f / (1.0f + __expf(-z));
}

__device__ __forceinline__ void gauss15(float* g) {
    float s = 0.f;
#pragma unroll
    for (int i = 0; i < 15; ++i) {
        float a = (float)i - 7.0f;
        g[i] = __expf(-a * a / 18.0f);   // 2*sigma^2 = 18
        s += g[i];
    }
    float inv = 1.0f / s;
#pragma unroll
    for (int i = 0; i < 15; ++i) g[i] *= inv;
}

// ---------------------------------------------------------------- K1: in_proj (U half only), one batch
// grid (HW/256, 2): blockIdx.y selects o-group of 64 (more blocks -> latency hiding)
__global__ __launch_bounds__(256) void k_inproj(
    const float* __restrict__ xb, const float* __restrict__ w,
    const float* __restrict__ bias, float* __restrict__ Ub) {
    int p = blockIdx.x * 256 + threadIdx.x;
    int og = blockIdx.y * 64;
    float xv[CIN];
#pragma unroll
    for (int c = 0; c < CIN; ++c) xv[c] = xb[(size_t)c * HW + p];
#pragma unroll 2
    for (int o = og; o < og + 64; ++o) {
        float a0 = bias[o], a1 = 0.f, a2 = 0.f, a3 = 0.f;
        const float* wr = w + o * CIN;
#pragma unroll
        for (int c = 0; c < CIN; c += 4) {
            a0 = fmaf(xv[c],     wr[c],     a0);
            a1 = fmaf(xv[c + 1], wr[c + 1], a1);
            a2 = fmaf(xv[c + 2], wr[c + 2], a2);
            a3 = fmaf(xv[c + 3], wr[c + 3], a3);
        }
        Ub[(size_t)o * HW + p] = (a0 + a1) + (a2 + a3);
    }
}

// ---------------------------------------------------------------- K2: fused dw3x3+tanh+15x15 highpass, one batch
#define TILE_H 16
__global__ __launch_bounds__(256) void k_conv(
    const float* __restrict__ Ub, const float* __restrict__ dww,
    const float* __restrict__ dwb, float* __restrict__ Ucb) {
    __shared__ float sU[32 * 256];
    __shared__ float sC[30 * 272];
    int c  = blockIdx.x >> 4;
    int t  = blockIdx.x & 15;
    int h0 = t * TILE_H;
    int w  = threadIdx.x;

    const float* base = Ub + (size_t)c * HW;
#pragma unroll
    for (int i = 0; i < 32; ++i) {
        int hh = h0 + i - 8;
        sU[i * 256 + w] = (hh >= 0 && hh < HH) ? base[hh * WW + w] : 0.f;
    }
    __syncthreads();

    float wt[9];
#pragma unroll
    for (int i = 0; i < 9; ++i) wt[i] = dww[c * 9 + i];
    float bb = dwb[c];

#pragma unroll
    for (int i = 0; i < 30; ++i) {
        int r = h0 + i - 7;
        float v = 0.f;
        if (r >= 0 && r < HH) {
            float acc = bb;
#pragma unroll
            for (int ky = 0; ky < 3; ++ky) {
                const float* ur = sU + (i + ky) * 256;
#pragma unroll
                for (int kx = 0; kx < 3; ++kx) {
                    int ww = w + kx - 1;
                    if (ww >= 0 && ww < WW) acc = fmaf(ur[ww], wt[ky * 3 + kx], acc);
                }
            }
            v = tanh_half(acc);
        }
        sC[i * 272 + w + 7] = v;
    }
    if (w < 7) {
#pragma unroll
        for (int i = 0; i < 30; ++i) { sC[i * 272 + w] = 0.f; sC[i * 272 + w + 263] = 0.f; }
    }
    __syncthreads();

    float g[15]; gauss15(g);
#pragma unroll
    for (int i = 0; i < 30; ++i) {
        float acc = 0.f;
#pragma unroll
        for (int k = 0; k < 15; ++k) acc = fmaf(sC[i * 272 + w + k], g[k], acc);
        sU[i * 256 + w] = acc;
    }
    float* outp = Ucb + (size_t)c * HW + h0 * WW + w;
#pragma unroll
    for (int i = 0; i < TILE_H; ++i) {
        float acc = 0.f;
#pragma unroll
        for (int k = 0; k < 15; ++k) acc = fmaf(sU[(i + k) * 256 + w], g[k], acc);
        float center = sC[(i + 7) * 272 + w + 7];
        outp[i * WW] = center - acc;
    }
}

// ---------------------------------------------------------------- K5: x_proj (128 -> 33), nb batches
__global__ __launch_bounds__(256) void k_xproj(
    const float* __restrict__ Uc, const float* __restrict__ xw,
    float* __restrict__ P) {
    int p = blockIdx.x * 256 + threadIdx.x;
    int b = p >> 16;
    int rem = p & 65535;
    const float* up = Uc + (size_t)b * DI * HW + rem;
    float acc[NCH_P];
#pragma unroll
    for (int o = 0; o < NCH_P; ++o) acc[o] = 0.f;
    for (int c = 0; c < DI; ++c) {
        float u = up[(size_t)c * HW];
#pragma unroll
        for (int o = 0; o < NCH_P; ++o) acc[o] = fmaf(u, xw[o * DI + c], acc[o]);
    }
    float* pp = P + (size_t)b * NCH_P * HW + rem;
#pragma unroll
    for (int o = 0; o < NCH_P; ++o) pp[(size_t)o * HW] = acc[o];
}

// ---------------------------------------------------------------- K6: scan along W, LDS-staged u AND P, reg-prefetch
#define CW 32
__global__ __launch_bounds__(128) void k_scan_w(
    float* __restrict__ UY, const float* __restrict__ P,
    const float* __restrict__ A_log, const float* __restrict__ dtw,
    const float* __restrict__ dtb, const float* __restrict__ Dv) {
    __shared__ float sU[DI * 33];
    __shared__ float sP[CW * 36];
    int bh = blockIdx.x;
    int b = bh >> 8;
    int h = bh & 255;
    int t = threadIdx.x;                   // d

    float Av[NS];
#pragma unroll
    for (int n = 0; n < NS; ++n) Av[n] = -__expf(A_log[t * NS + n]);
    float wdt = dtw[t], bdt = dtb[t], Dd = Dv[t];
    float hS[NS];
#pragma unroll
    for (int n = 0; n < NS; ++n) hS[n] = 0.f;

    float* ubase = UY + (size_t)(b * DI) * HW + (size_t)h * WW;
    const float* prow = P + (size_t)(b * NCH_P) * HW + (size_t)h * WW;

    const int w4 = (t & 7) * 4;
    const int dbase = t >> 3;

    float4 rU[8];
    float rP[9];
#pragma unroll
    for (int p = 0; p < 8; ++p)
        rU[p] = *(const float4*)(ubase + (size_t)(dbase + p * 16) * HW + w4);
#pragma unroll
    for (int i = 0; i < 9; ++i) {
        int idx = i * 128 + t, ch = idx >> 5, wi = idx & 31;
        rP[i] = (ch < NCH_P) ? prow[(size_t)ch * HW + wi] : 0.f;
    }

    for (int w0 = 0; w0 < WW; w0 += CW) {
#pragma unroll
        for (int p = 0; p < 8; ++p) {
            float* s = sU + (dbase + p * 16) * 33 + w4;
            s[0] = rU[p].x; s[1] = rU[p].y; s[2] = rU[p].z; s[3] = rU[p].w;
        }
#pragma unroll
        for (int i = 0; i < 9; ++i) {
            int idx = i * 128 + t, ch = idx >> 5, wi = idx & 31;
            if (ch < NCH_P) sP[wi * 36 + ch] = rP[i];
        }
        __syncthreads();
        if (w0 + CW < WW) {
#pragma unroll
            for (int p = 0; p < 8; ++p)
                rU[p] = *(const float4*)(ubase + (size_t)(dbase + p * 16) * HW + w0 + CW + w4);
#pragma unroll
            for (int i = 0; i < 9; ++i) {
                int idx = i * 128 + t, ch = idx >> 5, wi = idx & 31;
                rP[i] = (ch < NCH_P) ? prow[(size_t)ch * HW + w0 + CW + wi] : 0.f;
            }
        }
#pragma unroll 2
        for (int wi = 0; wi < CW; ++wi) {
            const float* pr = sP + wi * 36;
            float4 q0 = *(const float4*)(pr);
            float4 q1 = *(const float4*)(pr + 4);
            float4 q2 = *(const float4*)(pr + 8);
            float4 q3 = *(const float4*)(pr + 12);
            float4 q4 = *(const float4*)(pr + 16);
            float4 q5 = *(const float4*)(pr + 20);
            float4 q6 = *(const float4*)(pr + 24);
            float4 q7 = *(const float4*)(pr + 28);
            float q8 = pr[32];
            float u = sU[t * 33 + wi];
            float dt = softplusf(fmaf(q0.x, wdt, bdt));
            float ud = u * dt;
            float y = Dd * u;
            float Bv[NS] = {q0.y,q0.z,q0.w,q1.x,q1.y,q1.z,q1.w,q2.x,
                            q2.y,q2.z,q2.w,q3.x,q3.y,q3.z,q3.w,q4.x};
            float Cv[NS] = {q4.y,q4.z,q4.w,q5.x,q5.y,q5.z,q5.w,q6.x,
                            q6.y,q6.z,q6.w,q7.x,q7.y,q7.z,q7.w,q8};
#pragma unroll
            for (int n = 0; n < NS; ++n) {
                float e = __expf(dt * Av[n]);
                hS[n] = fmaf(e, hS[n], ud * Bv[n]);
                y = fmaf(hS[n], Cv[n], y);
            }
            sU[t * 33 + wi] = y;
        }
        __syncthreads();
#pragma unroll
        for (int p = 0; p < 8; ++p) {
            const float* s = sU + (dbase + p * 16) * 33 + w4;
            float4 v; v.x = s[0]; v.y = s[1]; v.z = s[2]; v.w = s[3];
            *(float4*)(ubase + (size_t)(dbase + p * 16) * HW + w0 + w4) = v;
        }
        __syncthreads();
    }
}

// ---------------------------------------------------------------- K7: scan along H, unroll x2, prefetch depth 2
__global__ __launch_bounds__(256) void k_scan_h(
    float* __restrict__ UY, const float* __restrict__ P,
    const float* __restrict__ A_log, const float* __restrict__ dtw,
    const float* __restrict__ dtb, const float* __restrict__ Dv) {
    int bd = blockIdx.x;
    int b = bd >> 7;
    int d = bd & (DI - 1);
    int w = threadIdx.x;
    float Av[NS];
#pragma unroll
    for (int n = 0; n < NS; ++n) Av[n] = -__expf(A_log[d * NS + n]);
    float wdt = dtw[d], bdt = dtb[d], Dd = Dv[d];
    float* ucol = UY + (size_t)bd * HW + w;
    const float* pcol = P + (size_t)(b * NCH_P) * HW + w;
    float hS[NS];
#pragma unroll
    for (int n = 0; n < NS; ++n) hS[n] = 0.f;

    float uA, deA, BA[NS], CA[NS];
    float uB, deB, Bb[NS], Cb[NS];
    uA = ucol[0]; deA = pcol[0];
#pragma unroll
    for (int n = 0; n < NS; ++n) { BA[n] = pcol[(size_t)(1 + n) * HW]; CA[n] = pcol[(size_t)(17 + n) * HW]; }
    uB = ucol[WW]; deB = pcol[WW];
#pragma unroll
    for (int n = 0; n < NS; ++n) { Bb[n] = pcol[(size_t)(1 + n) * HW + WW]; Cb[n] = pcol[(size_t)(17 + n) * HW + WW]; }

    for (int h = 0; h < HH; h += 2) {
        size_t o2 = (size_t)min(h + 2, HH - 1) * WW;
        size_t o3 = (size_t)min(h + 3, HH - 1) * WW;
        float u2 = ucol[o2], de2 = pcol[o2];
        float u3 = ucol[o3], de3 = pcol[o3];
        float B2[NS], C2[NS], B3[NS], C3[NS];
#pragma unroll
        for (int n = 0; n < NS; ++n) {
            B2[n] = pcol[(size_t)(1 + n) * HW + o2];
            C2[n] = pcol[(size_t)(17 + n) * HW + o2];
            B3[n] = pcol[(size_t)(1 + n) * HW + o3];
            C3[n] = pcol[(size_t)(17 + n) * HW + o3];
        }
        {
            float dt = softplusf(fmaf(deA, wdt, bdt));
            float ud = uA * dt;
            float y = Dd * uA;
#pragma unroll
            for (int n = 0; n < NS; ++n) {
                float e = __expf(dt * Av[n]);
                hS[n] = fmaf(e, hS[n], ud * BA[n]);
                y = fmaf(hS[n], CA[n], y);
            }
            ucol[(size_t)h * WW] = y;
        }
        {
            float dt = softplusf(fmaf(deB, wdt, bdt));
            float ud = uB * dt;
            float y = Dd * uB;
#pragma unroll
            for (int n = 0; n < NS; ++n) {
                float e = __expf(dt * Av[n]);
                hS[n] = fmaf(e, hS[n], ud * Bb[n]);
                y = fmaf(hS[n], Cb[n], y);
            }
            ucol[(size_t)(h + 1) * WW] = y;
        }
        uA = u2; deA = de2; uB = u3; deB = de3;
#pragma unroll
        for (int n = 0; n < NS; ++n) { BA[n] = B2[n]; CA[n] = C2[n]; Bb[n] = B3[n]; Cb[n] = C3[n]; }
    }
}

// ---------------------------------------------------------------- K8a: gate in-place: Y <- Y * sigmoid(Wz x + bz)
// Holds only xv[64] in registers -> no rematerialization.
__global__ __launch_bounds__(256) void k_gate(
    float* __restrict__ Y, const float* __restrict__ x,
    const float* __restrict__ wz, const float* __restrict__ bz) {
    int p = blockIdx.x * 256 + threadIdx.x;
    int b = p >> 16;
    int rem = p & 65535;
    const float* xp = x + (size_t)b * CIN * HW + rem;
    float xv[CIN];
#pragma unroll
    for (int c = 0; c < CIN; ++c) xv[c] = xp[(size_t)c * HW];
    float* yp = Y + (size_t)b * DI * HW + rem;
#pragma unroll 2
    for (int dd = 0; dd < DI; ++dd) {
        float z0 = 0.f, z1 = 0.f, z2 = 0.f, z3 = 0.f;
        const float* wr = wz + dd * CIN;
#pragma unroll
        for (int c = 0; c < CIN; c += 4) {
            z0 = fmaf(xv[c],     wr[c],     z0);
            z1 = fmaf(xv[c + 1], wr[c + 1], z1);
            z2 = fmaf(xv[c + 2], wr[c + 2], z2);
            z3 = fmaf(xv[c + 3], wr[c + 3], z3);
        }
        float z = bz[dd] + ((z0 + z1) + (z2 + z3));
        float yv = yp[(size_t)dd * HW];
        yp[(size_t)dd * HW] = yv * sigmoidf(z);
    }
}

// ---------------------------------------------------------------- K8b: out = Wo * G + ob
// Holds only acc[64] in registers; streams G coalesced.
__global__ __launch_bounds__(256) void k_out2(
    const float* __restrict__ G, const float* __restrict__ ow,
    const float* __restrict__ ob, float* __restrict__ outp) {
    int p = blockIdx.x * 256 + threadIdx.x;
    int b = p >> 16;
    int rem = p & 65535;
    const float* gp = G + (size_t)b * DI * HW + rem;
    float acc[CIN];
#pragma unroll
    for (int c = 0; c < CIN; ++c) acc[c] = 0.f;
    for (int dd = 0; dd < DI; ++dd) {
        float g = gp[(size_t)dd * HW];
#pragma unroll
        for (int c = 0; c < CIN; ++c) acc[c] = fmaf(g, ow[c * DI + dd], acc[c]);
    }
    float* op = outp + (size_t)b * CIN * HW + rem;
#pragma unroll
    for (int c = 0; c < CIN; ++c) op[(size_t)c * HW] = acc[c] + ob[c];
}

// ---------------------------------------------------------------- launch
extern "C" void kernel_launch(void* const* d_in, const int* in_sizes, int n_in,
                              void* d_out, int out_size, void* d_ws, size_t ws_size,
                              hipStream_t stream) {
    const float* x     = (const float*)d_in[0];
    const float* ipw   = (const float*)d_in[1];
    const float* ipb   = (const float*)d_in[2];
    const float* dww   = (const float*)d_in[3];
    const float* dwb   = (const float*)d_in[4];
    const float* xpw   = (const float*)d_in[5];
    const float* dtw   = (const float*)d_in[6];
    const float* dtb   = (const float*)d_in[7];
    const float* A_log = (const float*)d_in[8];
    const float* Dv    = (const float*)d_in[9];
    const float* ow    = (const float*)d_in[10];
    const float* ob    = (const float*)d_in[11];
    float* out = (float*)d_out;

    const float* wz = ipw + (size_t)DI * CIN;
    const float* bz = ipb + DI;

    const size_t PLANE = (size_t)DI * HW;
    const size_t NB    = (size_t)BB * PLANE;

    if (ws_size >= (NB + PLANE) * sizeof(float)) {
        // ---------- Path A: full-batch scans. ws = Y(4) + U(1); P staged in d_out.
        float* bufY = (float*)d_ws;
        float* bufU = bufY + NB;
        float* P    = out;
        for (int b = 0; b < BB; ++b) {
            k_inproj<<<dim3(HW / 256, 2), 256, 0, stream>>>(x + (size_t)b * CIN * HW, ipw, ipb, bufU);
            k_conv<<<DI * 16, 256, 0, stream>>>(bufU, dww, dwb, bufY + (size_t)b * PLANE);
        }
        k_xproj<<<BB * (HW / 256), 256, 0, stream>>>(bufY, xpw, P);
        k_scan_w<<<BB * HH, 128, 0, stream>>>(bufY, P, A_log, dtw, dtb, Dv);
        k_scan_h<<<BB * DI, 256, 0, stream>>>(bufY, P, A_log, dtw, dtb, Dv);
        k_gate<<<BB * (HW / 256), 256, 0, stream>>>(bufY, x, wz, bz);
        k_out2<<<BB * (HW / 256), 256, 0, stream>>>(bufY, ow, ob, out);
    } else {
        // ---------- Path B: batch-sequential. ws = U_b/P_b (overlapped) + Y_b.
        float* bufA = (float*)d_ws;
        float* bufY = bufA + PLANE;
        for (int b = 0; b < BB; ++b) {
            const float* xb = x + (size_t)b * CIN * HW;
            k_inproj<<<dim3(HW / 256, 2), 256, 0, stream>>>(xb, ipw, ipb, bufA);
            k_conv<<<DI * 16, 256, 0, stream>>>(bufA, dww, dwb, bufY);
            k_xproj<<<HW / 256, 256, 0, stream>>>(bufY, xpw, bufA);
            k_scan_w<<<HH, 128, 0, stream>>>(bufY, bufA, A_log, dtw, dtb, Dv);
            k_scan_h<<<DI, 256, 0, stream>>>(bufY, bufA, A_log, dtw, dtb, Dv);
            k_gate<<<HW / 256, 256, 0, stream>>>(bufY, xb, wz, bz);
            k_out2<<<HW / 256, 256, 0, stream>>>(bufY, ow, ob, out + (size_t)b * CIN * HW);
        }
    }
}